// Round 9
// baseline (209.825 us; speedup 1.0000x reference)
//
#include <hip/hip_runtime.h>
#include <hip/hip_bf16.h>
#include <cstddef>

// MultiHeadAttention: B=2, S=2048, E=1024, H=16, D=64. I/O fp32, compute bf16.
#define SEQ   2048
#define EMB   1024
#define NHEAD 16
#define HDIM  64
#define BATCH 2
#define MROWS (BATCH * SEQ)   // 4096
#define BH_STRIDE (SEQ * HDIM)
#define CSC_F 0.180336874f    // 0.125 * log2(e), folded into Wq/bq

typedef __attribute__((ext_vector_type(8))) short frag_ab;   // 8 bf16 = 4 VGPR
typedef __attribute__((ext_vector_type(4))) float frag_cd;   // 4 fp32 acc

#define GLOBAL_AS __attribute__((address_space(1)))
#define LDS_AS    __attribute__((address_space(3)))

__device__ __forceinline__ unsigned short f2bf(float f) {      // RNE
    unsigned u = __float_as_uint(f);
    u += 0x7FFF + ((u >> 16) & 1);
    return (unsigned short)(u >> 16);
}
__device__ __forceinline__ unsigned short f2bf_trunc(float f) { // truncate (P only)
    return (unsigned short)(__float_as_uint(f) >> 16);
}
__device__ __forceinline__ void gld16(const unsigned short* g, unsigned short* l) {
    __builtin_amdgcn_global_load_lds((GLOBAL_AS const unsigned int*)g,
                                     (LDS_AS unsigned int*)l, 16, 0, 0);
}

// ---------------------------------------------------------------------------
// One-shot fp32->bf16 for x + Wq(*csc) + Wk + Wv (block-aligned regions).
// ---------------------------------------------------------------------------
__global__ __launch_bounds__(256) void cvt_all(const float* __restrict__ x,
                                               const float* __restrict__ Wq,
                                               const float* __restrict__ Wk,
                                               const float* __restrict__ Wv,
                                               unsigned short* __restrict__ xb,
                                               unsigned short* __restrict__ wqkv) {
    size_t e = ((size_t)blockIdx.x * 256 + threadIdx.x) * 8;
    const float* s;
    unsigned short* d;
    float sc = 1.0f;
    const size_t NX = (size_t)MROWS * EMB;
    const size_t NW = (size_t)EMB * EMB;
    if (e < NX) { s = x + e; d = xb + e; }
    else if (e < NX + NW)     { s = Wq + (e - NX);          d = wqkv + (e - NX); sc = CSC_F; }
    else if (e < NX + 2 * NW) { s = Wk + (e - NX - NW);     d = wqkv + (e - NX); }
    else                      { s = Wv + (e - NX - 2 * NW); d = wqkv + (e - NX); }
    float4 f0 = *(const float4*)s;
    float4 f1 = *(const float4*)(s + 4);
    ushort4 lo, hi;
    lo.x = f2bf(f0.x * sc); lo.y = f2bf(f0.y * sc); lo.z = f2bf(f0.z * sc); lo.w = f2bf(f0.w * sc);
    hi.x = f2bf(f1.x * sc); hi.y = f2bf(f1.y * sc); hi.z = f2bf(f1.z * sc); hi.w = f2bf(f1.w * sc);
    *(ushort4*)d = lo;
    *(ushort4*)(d + 4) = hi;
}

__global__ __launch_bounds__(256) void cvt_bf16(const float* __restrict__ s,
                                                unsigned short* __restrict__ d, int n) {
    int i = (blockIdx.x * 256 + threadIdx.x) * 8;
    if (i >= n) return;
    float4 f0 = *(const float4*)&s[i];
    float4 f1 = *(const float4*)&s[i + 4];
    ushort4 lo, hi;
    lo.x = f2bf(f0.x); lo.y = f2bf(f0.y); lo.z = f2bf(f0.z); lo.w = f2bf(f0.w);
    hi.x = f2bf(f1.x); hi.y = f2bf(f1.y); hi.z = f2bf(f1.z); hi.w = f2bf(f1.w);
    *(ushort4*)&d[i] = lo;
    *(ushort4*)&d[i + 4] = hi;
}

// ---------------------------------------------------------------------------
// 128x128x64 GEMM: C = A.W^T + bias. A,W bf16 via global_load_lds width=16.
// __launch_bounds__(256,3): 3 blocks/CU (m97 regime) -> 768-grid co-resident.
// 1-D grid, XCD-aware decode (xcd = b&7 owns 4 m-strips).
// QKV=true: 768 blocks, z selects weight; LDS-assembled fragment-layout
//   epilogue, 1KB coalesced bursts. QKV=false: 256 blocks, fp32 row-major.
// ---------------------------------------------------------------------------
template <bool QKV>
__global__ __launch_bounds__(256, 3) void gemm128(const unsigned short* __restrict__ A,
                                                  const unsigned short* __restrict__ W0,
                                                  const unsigned short* __restrict__ W1,
                                                  const unsigned short* __restrict__ W2,
                                                  const float* __restrict__ b0,
                                                  const float* __restrict__ b1,
                                                  const float* __restrict__ b2,
                                                  void* __restrict__ o0,
                                                  void* __restrict__ o1,
                                                  void* __restrict__ o2) {
    constexpr int K = EMB;
    __shared__ __align__(16) unsigned short SB[16384];
    unsigned short* As = SB;
    unsigned short* Bs = SB + 8192;

    const int bidx = blockIdx.x;
    const int g8 = bidx & 7, t = bidx >> 3;
    const int my = g8 * 4 + (t & 3);
    const int mx = QKV ? ((t >> 2) & 7) : (t >> 2);
    const int z = QKV ? (t >> 5) : 0;

    const unsigned short* W = (z == 0) ? W0 : (z == 1) ? W1 : W2;
    const float* bias = (z == 0) ? b0 : (z == 1) ? b1 : b2;
    void* outv = (z == 0) ? o0 : (z == 1) ? o1 : o2;

    const int m0 = my * 128;
    const int n0 = mx * 128;
    const int tid = threadIdx.x;
    const int lane = tid & 63, w = tid >> 6;
    const int wr = w >> 1, wc = w & 1;
    const int lm = lane & 15, lq = lane >> 4;

    frag_cd acc[4][4];
#pragma unroll
    for (int mt = 0; mt < 4; ++mt)
#pragma unroll
        for (int nt = 0; nt < 4; ++nt) acc[mt][nt] = (frag_cd){0.f, 0.f, 0.f, 0.f};

    for (int k0 = 0; k0 < K; k0 += 64) {
#pragma unroll
        for (int it = 0; it < 4; ++it) {
            int flat = (it * 256 + tid) * 8;
            int r = flat >> 6, c = flat & 63;
            gld16(&A[(size_t)(m0 + r) * K + k0 + c], &As[flat]);
        }
#pragma unroll
        for (int it = 0; it < 4; ++it) {
            int flat = (it * 256 + tid) * 8;
            int r = flat >> 6, c = flat & 63;
            gld16(&W[(size_t)(n0 + r) * K + k0 + c], &Bs[flat]);
        }
        __syncthreads();

#pragma unroll
        for (int kk = 0; kk < 2; ++kk) {
            frag_ab af[4], bf[4];
#pragma unroll
            for (int mt = 0; mt < 4; ++mt)
                af[mt] = *(const frag_ab*)&As[(wr * 64 + mt * 16 + lm) * 64 + kk * 32 + lq * 8];
#pragma unroll
            for (int nt = 0; nt < 4; ++nt)
                bf[nt] = *(const frag_ab*)&Bs[(wc * 64 + nt * 16 + lm) * 64 + kk * 32 + lq * 8];
#pragma unroll
            for (int mt = 0; mt < 4; ++mt)
#pragma unroll
                for (int nt = 0; nt < 4; ++nt)
                    acc[mt][nt] = __builtin_amdgcn_mfma_f32_16x16x32_bf16(
                        af[mt], bf[nt], acc[mt][nt], 0, 0, 0);
        }
        __syncthreads();
    }

    const float bscale = (QKV && z == 0) ? CSC_F : 1.0f;
    if (!QKV) {
#pragma unroll
        for (int mt = 0; mt < 4; ++mt)
#pragma unroll
            for (int nt = 0; nt < 4; ++nt) {
                int col = n0 + wc * 64 + nt * 16 + lm;
                float bv = bias[col];
#pragma unroll
                for (int r = 0; r < 4; ++r) {
                    int row = m0 + wr * 64 + mt * 16 + lq * 4 + r;
                    ((float*)outv)[(size_t)row * EMB + col] = acc[mt][nt][r] + bv;
                }
            }
    } else {
#pragma unroll
        for (int mt = 0; mt < 4; ++mt)
#pragma unroll
            for (int nt = 0; nt < 4; ++nt) {
                int col = n0 + wc * 64 + nt * 16 + lm;
                float bv = bias[col] * bscale;
#pragma unroll
                for (int r = 0; r < 4; ++r) {
                    unsigned short o = f2bf(acc[mt][nt][r] + bv);
                    int l, pos;
                    if (z < 2) {   // Q/K frag layout
                        l = wc * 16 + (wr * 4 + mt) * 2 + (nt >> 1);
                        pos = ((nt * 2 + (lm >> 3)) & 3) * 128 + (lq * 4 + r) * 8 + (lm & 7);
                    } else {       // V^T frag layout
                        l = wc * 16 + (wr * 2 + (mt >> 1)) * 4 + nt;
                        pos = ((mt & 1) * 2 + (lq >> 1)) * 128 + lm * 8 + (lq & 1) * 4 + r;
                    }
                    SB[l * 512 + pos] = o;
                }
            }
        __syncthreads();

        unsigned short* out = (unsigned short*)outv;
        const int b = m0 >> 11;
        const int hb = n0 >> 6;
        const int sg16 = (m0 & (SEQ - 1)) >> 4;
        const int sb32 = (m0 & (SEQ - 1)) >> 5;
#pragma unroll
        for (int it = 0; it < 8; ++it) {
            int cl = it * 4 + w;
            uint4 v = *(const uint4*)&SB[cl * 512 + lane * 8];
            size_t chunk;
            if (z < 2) {
                int h = cl >> 4, sg = (cl >> 1) & 7, dh = cl & 1;
                chunk = ((size_t)(b * NHEAD + hb + h) * 128 + sg16 + sg) * 2 + dh;
            } else {
                int h = cl >> 4, sb = (cl >> 2) & 3, dq = cl & 3;
                chunk = ((size_t)(b * NHEAD + hb + h) * 64 + sb32 + sb) * 4 + dq;
            }
            *(uint4*)&out[chunk * 512 + lane * 8] = v;
        }
    }
}

// ---------------------------------------------------------------------------
// Flash attention (no-max softmax, Q pre-scaled): 512 blocks, XCD swizzle.
// K/V tiles staged ONCE per block into LDS (shared by 4 waves, 4x traffic
// cut) with a double-buffered ONE-barrier pipeline: stage(i+1) is issued
// right after the barrier that publishes buffer i, then compute(i) runs
// before the next barrier drains it -> load latency fully hidden.
// Both K-frag and V-frag global layouts are CONTIGUOUS 8 KB per 64-key tile
// (base = bh*BH_STRIDE + j0*64), so staging is 4 gld16 per thread.
// ---------------------------------------------------------------------------
#define PSTRIDE 72
__global__ __launch_bounds__(256) void attn_fused(const unsigned short* __restrict__ Q,
                                                  const unsigned short* __restrict__ Kf,
                                                  const unsigned short* __restrict__ Vf,
                                                  unsigned short* __restrict__ O) {
    const int bidx = blockIdx.x;
    const int g8 = bidx & 7, t = bidx >> 3;
    const int bh = g8 * 4 + (t & 3);
    const int qt = t >> 2;
    const int tid = threadIdx.x;
    const int w = tid >> 6, lane = tid & 63;
    const int lm = lane & 15, lq = lane >> 4;

    __shared__ __align__(16) unsigned short Ks[2][4096];   // 8 KB x2
    __shared__ __align__(16) unsigned short Vs[2][4096];   // 8 KB x2
    __shared__ __align__(16) unsigned short P[4][32 * PSTRIDE];  // 18.4 KB

    const unsigned short* Qb = Q + (size_t)bh * BH_STRIDE;
    const unsigned short* Kb = Kf + (size_t)bh * BH_STRIDE;
    const unsigned short* Vb = Vf + (size_t)bh * BH_STRIDE;

    const int ga = qt * 8 + w * 2;
    frag_ab qf[2][2];
#pragma unroll
    for (int qi = 0; qi < 2; ++qi) {
        qf[qi][0] = *(const frag_ab*)&Qb[(((ga + qi) * 2 + 0) * 64 + lane) * 8];
        qf[qi][1] = *(const frag_ab*)&Qb[(((ga + qi) * 2 + 1) * 64 + lane) * 8];
    }

    frag_ab vone;
#pragma unroll
    for (int j = 0; j < 8; ++j) vone[j] = (short)0x3F80;   // bf16 1.0

    frag_cd oa[2][4], oc[2];
#pragma unroll
    for (int qi = 0; qi < 2; ++qi) {
        oc[qi] = (frag_cd){0.f, 0.f, 0.f, 0.f};
#pragma unroll
        for (int dt = 0; dt < 4; ++dt) oa[qi][dt] = (frag_cd){0.f, 0.f, 0.f, 0.f};
    }

    // stage(tile j0 -> buffer buf): 8 KB K + 8 KB V, 4 gld16 per thread.
    // flat = (it*4 + w)*512 + lane*8  (wave-uniform LDS base + lane*16B)
    auto stage = [&](int buf, int j0) {
#pragma unroll
        for (int it = 0; it < 2; ++it) {
            int flat = (it * 256 + tid) * 8;
            gld16(&Kb[(size_t)j0 * 64 + flat], &Ks[buf][flat]);
            gld16(&Vb[(size_t)j0 * 64 + flat], &Vs[buf][flat]);
        }
    };

    stage(0, 0);

    for (int it = 0; it < SEQ / 64; ++it) {
        __syncthreads();                 // publishes buffer it&1 (drains stage)
        const int cur = it & 1;
        if (it + 1 < SEQ / 64) stage(cur ^ 1, (it + 1) * 64);

        // QK^T + exp2 from LDS K
        const frag_cd z = (frag_cd){0.f, 0.f, 0.f, 0.f};
#pragma unroll
        for (int c = 0; c < 4; ++c) {
            frag_ab k0 = *(const frag_ab*)&Ks[cur][((c * 2 + 0) * 64 + lane) * 8];
            frag_ab k1 = *(const frag_ab*)&Ks[cur][((c * 2 + 1) * 64 + lane) * 8];
#pragma unroll
            for (int qi = 0; qi < 2; ++qi) {
                frag_cd s = __builtin_amdgcn_mfma_f32_16x16x32_bf16(qf[qi][0], k0, z, 0, 0, 0);
                s = __builtin_amdgcn_mfma_f32_16x16x32_bf16(qf[qi][1], k1, s, 0, 0, 0);
#pragma unroll
                for (int r = 0; r < 4; ++r) {
                    float p = __builtin_amdgcn_exp2f(s[r]);
                    P[w][(qi * 16 + lq * 4 + r) * PSTRIDE + c * 16 + lm] = f2bf_trunc(p);
                }
            }
        }

        // C-layout -> A-layout via wave-local LDS (in-order DS, no barrier)
        frag_ab pf[2][2];
#pragma unroll
        for (int qi = 0; qi < 2; ++qi) {
            pf[qi][0] = *(const frag_ab*)&P[w][(qi * 16 + lm) * PSTRIDE + lq * 8];
            pf[qi][1] = *(const frag_ab*)&P[w][(qi * 16 + lm) * PSTRIDE + 32 + lq * 8];
            oc[qi] = __builtin_amdgcn_mfma_f32_16x16x32_bf16(pf[qi][0], vone, oc[qi], 0, 0, 0);
            oc[qi] = __builtin_amdgcn_mfma_f32_16x16x32_bf16(pf[qi][1], vone, oc[qi], 0, 0, 0);
        }

        // PV from LDS V
#pragma unroll
        for (int dt = 0; dt < 4; ++dt) {
            frag_ab v0 = *(const frag_ab*)&Vs[cur][((0 * 4 + dt) * 64 + lane) * 8];
            frag_ab v1 = *(const frag_ab*)&Vs[cur][((1 * 4 + dt) * 64 + lane) * 8];
#pragma unroll
            for (int qi = 0; qi < 2; ++qi) {
                oa[qi][dt] = __builtin_amdgcn_mfma_f32_16x16x32_bf16(pf[qi][0], v0, oa[qi][dt], 0, 0, 0);
                oa[qi][dt] = __builtin_amdgcn_mfma_f32_16x16x32_bf16(pf[qi][1], v1, oa[qi][dt], 0, 0, 0);
            }
        }
    }

    const int b = bh >> 4, h = bh & (NHEAD - 1);
#pragma unroll
    for (int qi = 0; qi < 2; ++qi) {
        const int q0 = (ga + qi) * 16;
#pragma unroll
        for (int r = 0; r < 4; ++r) {
            float inv = 1.0f / oc[qi][r];
            int srow = q0 + lq * 4 + r;
#pragma unroll
            for (int dt = 0; dt < 4; ++dt) {
                int d = dt * 16 + lm;
                O[((size_t)(b * SEQ + srow)) * EMB + h * HDIM + d] = f2bf(oa[qi][dt][r] * inv);
            }
        }
    }
}

// ---------------------------------------------------------------------------
extern "C" void kernel_launch(void* const* d_in, const int* in_sizes, int n_in,
                              void* d_out, int out_size, void* d_ws, size_t ws_size,
                              hipStream_t stream) {
    const float* x  = (const float*)d_in[0];
    const float* Wq = (const float*)d_in[1];
    const float* bq = (const float*)d_in[2];
    const float* Wk = (const float*)d_in[3];
    const float* bk = (const float*)d_in[4];
    const float* Wv = (const float*)d_in[5];
    const float* bv = (const float*)d_in[6];
    const float* Wo = (const float*)d_in[7];
    const float* bo = (const float*)d_in[8];

    unsigned short* xb    = (unsigned short*)d_ws;
    unsigned short* q_ws  = xb + (size_t)MROWS * EMB;
    unsigned short* k_ws  = q_ws + (size_t)MROWS * EMB;
    unsigned short* vt_ws = k_ws + (size_t)MROWS * EMB;
    unsigned short* o_ws  = xb;     // xb dead after QKV projections
    unsigned short* wqkv  = (unsigned short*)d_out;   // d_out as bf16-W scratch
    unsigned short* wo_b  = q_ws;   // q_ws dead after attn; holds bf16 Wo

    dim3 blk(256);
    cvt_all<<<dim3((MROWS * EMB + 3 * EMB * EMB) / 2048), blk, 0, stream>>>(
        x, Wq, Wk, Wv, xb, wqkv);

    gemm128<true><<<dim3(768), blk, 0, stream>>>(
        xb, wqkv, wqkv + EMB * EMB, wqkv + 2 * EMB * EMB,
        bq, bk, bv, q_ws, k_ws, vt_ws);

    attn_fused<<<dim3(512), blk, 0, stream>>>(q_ws, k_ws, vt_ws, o_ws);

    cvt_bf16<<<dim3(EMB * EMB / 2048), blk, 0, stream>>>(Wo, wo_b, EMB * EMB);
    gemm128<false><<<dim3(256), blk, 0, stream>>>(
        o_ws, wo_b, wo_b, wo_b, bo, bo, bo, d_out, d_out, d_out);
}

// Round 10
// 186.917 us; speedup vs baseline: 1.1226x; 1.1226x over previous
//
#include <hip/hip_runtime.h>
#include <hip/hip_bf16.h>
#include <cstddef>

// MultiHeadAttention: B=2, S=2048, E=1024, H=16, D=64. I/O fp32, compute bf16.
#define SEQ   2048
#define EMB   1024
#define NHEAD 16
#define HDIM  64
#define BATCH 2
#define MROWS (BATCH * SEQ)   // 4096
#define BH_STRIDE (SEQ * HDIM)
#define CSC_F 0.180336874f    // 0.125 * log2(e), folded into Wq/bq

typedef __attribute__((ext_vector_type(8))) short frag_ab;   // 8 bf16 = 4 VGPR
typedef __attribute__((ext_vector_type(4))) float frag_cd;   // 4 fp32 acc

#define GLOBAL_AS __attribute__((address_space(1)))
#define LDS_AS    __attribute__((address_space(3)))

__device__ __forceinline__ unsigned short f2bf(float f) {      // RNE
    unsigned u = __float_as_uint(f);
    u += 0x7FFF + ((u >> 16) & 1);
    return (unsigned short)(u >> 16);
}
__device__ __forceinline__ unsigned short f2bf_trunc(float f) { // truncate (P only)
    return (unsigned short)(__float_as_uint(f) >> 16);
}
__device__ __forceinline__ void gld16(const unsigned short* g, unsigned short* l) {
    __builtin_amdgcn_global_load_lds((GLOBAL_AS const unsigned int*)g,
                                     (LDS_AS unsigned int*)l, 16, 0, 0);
}

// ---------------------------------------------------------------------------
// One-shot fp32->bf16 for x + Wq(*csc) + Wk + Wv (block-aligned regions).
// ---------------------------------------------------------------------------
__global__ __launch_bounds__(256) void cvt_all(const float* __restrict__ x,
                                               const float* __restrict__ Wq,
                                               const float* __restrict__ Wk,
                                               const float* __restrict__ Wv,
                                               unsigned short* __restrict__ xb,
                                               unsigned short* __restrict__ wqkv) {
    size_t e = ((size_t)blockIdx.x * 256 + threadIdx.x) * 8;
    const float* s;
    unsigned short* d;
    float sc = 1.0f;
    const size_t NX = (size_t)MROWS * EMB;
    const size_t NW = (size_t)EMB * EMB;
    if (e < NX) { s = x + e; d = xb + e; }
    else if (e < NX + NW)     { s = Wq + (e - NX);          d = wqkv + (e - NX); sc = CSC_F; }
    else if (e < NX + 2 * NW) { s = Wk + (e - NX - NW);     d = wqkv + (e - NX); }
    else                      { s = Wv + (e - NX - 2 * NW); d = wqkv + (e - NX); }
    float4 f0 = *(const float4*)s;
    float4 f1 = *(const float4*)(s + 4);
    ushort4 lo, hi;
    lo.x = f2bf(f0.x * sc); lo.y = f2bf(f0.y * sc); lo.z = f2bf(f0.z * sc); lo.w = f2bf(f0.w * sc);
    hi.x = f2bf(f1.x * sc); hi.y = f2bf(f1.y * sc); hi.z = f2bf(f1.z * sc); hi.w = f2bf(f1.w * sc);
    *(ushort4*)d = lo;
    *(ushort4*)(d + 4) = hi;
}

__global__ __launch_bounds__(256) void cvt_bf16(const float* __restrict__ s,
                                                unsigned short* __restrict__ d, int n) {
    int i = (blockIdx.x * 256 + threadIdx.x) * 8;
    if (i >= n) return;
    float4 f0 = *(const float4*)&s[i];
    float4 f1 = *(const float4*)&s[i + 4];
    ushort4 lo, hi;
    lo.x = f2bf(f0.x); lo.y = f2bf(f0.y); lo.z = f2bf(f0.z); lo.w = f2bf(f0.w);
    hi.x = f2bf(f1.x); hi.y = f2bf(f1.y); hi.z = f2bf(f1.z); hi.w = f2bf(f1.w);
    *(ushort4*)&d[i] = lo;
    *(ushort4*)&d[i + 4] = hi;
}

// ---------------------------------------------------------------------------
// 128x128x64 GEMM, XOR-SWIZZLED LDS: chunk c of row r lives at slot c^(r&7).
// Kills the 16-way bank conflict of stride-128B rows (bank = slot*4, spread
// over 8 groups by lm) while keeping gld16's contiguous wave-uniform dest:
// only the SOURCE chunk per lane is permuted inside the same 128-B segment.
// 1-D grid, XCD-aware decode. QKV=true: LDS-assembled fragment-layout
// epilogue; QKV=false: fp32 row-major.
// ---------------------------------------------------------------------------
template <bool QKV>
__global__ __launch_bounds__(256, 3) void gemm128(const unsigned short* __restrict__ A,
                                                  const unsigned short* __restrict__ W0,
                                                  const unsigned short* __restrict__ W1,
                                                  const unsigned short* __restrict__ W2,
                                                  const float* __restrict__ b0,
                                                  const float* __restrict__ b1,
                                                  const float* __restrict__ b2,
                                                  void* __restrict__ o0,
                                                  void* __restrict__ o1,
                                                  void* __restrict__ o2) {
    constexpr int K = EMB;
    __shared__ __align__(16) unsigned short SB[16384];
    unsigned short* As = SB;
    unsigned short* Bs = SB + 8192;

    const int bidx = blockIdx.x;
    const int g8 = bidx & 7, t = bidx >> 3;
    const int my = g8 * 4 + (t & 3);
    const int mx = QKV ? ((t >> 2) & 7) : (t >> 2);
    const int z = QKV ? (t >> 5) : 0;

    const unsigned short* W = (z == 0) ? W0 : (z == 1) ? W1 : W2;
    const float* bias = (z == 0) ? b0 : (z == 1) ? b1 : b2;
    void* outv = (z == 0) ? o0 : (z == 1) ? o1 : o2;

    const int m0 = my * 128;
    const int n0 = mx * 128;
    const int tid = threadIdx.x;
    const int lane = tid & 63, w = tid >> 6;
    const int wr = w >> 1, wc = w & 1;
    const int lm = lane & 15, lq = lane >> 4;

    // swizzled source chunk offset for staging (lane-only, hoisted):
    // logical chunk = (tid&7) ^ (row&7), row&7 = (tid>>3)&7
    const int cs = (((tid & 7) ^ ((tid >> 3) & 7)) << 3);
    const int sx = lm & 7;   // fragment-row swizzle key (row&7 == lm&7)

    frag_cd acc[4][4];
#pragma unroll
    for (int mt = 0; mt < 4; ++mt)
#pragma unroll
        for (int nt = 0; nt < 4; ++nt) acc[mt][nt] = (frag_cd){0.f, 0.f, 0.f, 0.f};

    for (int k0 = 0; k0 < K; k0 += 64) {
#pragma unroll
        for (int it = 0; it < 4; ++it) {
            int flat = (it * 256 + tid) * 8;
            int r = flat >> 6;
            gld16(&A[(size_t)(m0 + r) * K + k0 + cs], &As[flat]);
        }
#pragma unroll
        for (int it = 0; it < 4; ++it) {
            int flat = (it * 256 + tid) * 8;
            int r = flat >> 6;
            gld16(&W[(size_t)(n0 + r) * K + k0 + cs], &Bs[flat]);
        }
        __syncthreads();

#pragma unroll
        for (int kk = 0; kk < 2; ++kk) {
            frag_ab af[4], bf[4];
#pragma unroll
            for (int mt = 0; mt < 4; ++mt)
                af[mt] = *(const frag_ab*)&As[(wr * 64 + mt * 16 + lm) * 64
                                              + (((kk * 4 + lq) ^ sx) << 3)];
#pragma unroll
            for (int nt = 0; nt < 4; ++nt)
                bf[nt] = *(const frag_ab*)&Bs[(wc * 64 + nt * 16 + lm) * 64
                                              + (((kk * 4 + lq) ^ sx) << 3)];
#pragma unroll
            for (int mt = 0; mt < 4; ++mt)
#pragma unroll
                for (int nt = 0; nt < 4; ++nt)
                    acc[mt][nt] = __builtin_amdgcn_mfma_f32_16x16x32_bf16(
                        af[mt], bf[nt], acc[mt][nt], 0, 0, 0);
        }
        __syncthreads();
    }

    const float bscale = (QKV && z == 0) ? CSC_F : 1.0f;
    if (!QKV) {
#pragma unroll
        for (int mt = 0; mt < 4; ++mt)
#pragma unroll
            for (int nt = 0; nt < 4; ++nt) {
                int col = n0 + wc * 64 + nt * 16 + lm;
                float bv = bias[col];
#pragma unroll
                for (int r = 0; r < 4; ++r) {
                    int row = m0 + wr * 64 + mt * 16 + lq * 4 + r;
                    ((float*)outv)[(size_t)row * EMB + col] = acc[mt][nt][r] + bv;
                }
            }
    } else {
#pragma unroll
        for (int mt = 0; mt < 4; ++mt)
#pragma unroll
            for (int nt = 0; nt < 4; ++nt) {
                int col = n0 + wc * 64 + nt * 16 + lm;
                float bv = bias[col] * bscale;
#pragma unroll
                for (int r = 0; r < 4; ++r) {
                    unsigned short o = f2bf(acc[mt][nt][r] + bv);
                    int l, pos;
                    if (z < 2) {   // Q/K frag layout
                        l = wc * 16 + (wr * 4 + mt) * 2 + (nt >> 1);
                        pos = ((nt * 2 + (lm >> 3)) & 3) * 128 + (lq * 4 + r) * 8 + (lm & 7);
                    } else {       // V^T frag layout
                        l = wc * 16 + (wr * 2 + (mt >> 1)) * 4 + nt;
                        pos = ((mt & 1) * 2 + (lq >> 1)) * 128 + lm * 8 + (lq & 1) * 4 + r;
                    }
                    SB[l * 512 + pos] = o;
                }
            }
        __syncthreads();

        unsigned short* out = (unsigned short*)outv;
        const int b = m0 >> 11;
        const int hb = n0 >> 6;
        const int sg16 = (m0 & (SEQ - 1)) >> 4;
        const int sb32 = (m0 & (SEQ - 1)) >> 5;
#pragma unroll
        for (int it = 0; it < 8; ++it) {
            int cl = it * 4 + w;
            uint4 v = *(const uint4*)&SB[cl * 512 + lane * 8];
            size_t chunk;
            if (z < 2) {
                int h = cl >> 4, sg = (cl >> 1) & 7, dh = cl & 1;
                chunk = ((size_t)(b * NHEAD + hb + h) * 128 + sg16 + sg) * 2 + dh;
            } else {
                int h = cl >> 4, sb = (cl >> 2) & 3, dq = cl & 3;
                chunk = ((size_t)(b * NHEAD + hb + h) * 64 + sb32 + sb) * 4 + dq;
            }
            *(uint4*)&out[chunk * 512 + lane * 8] = v;
        }
    }
}

// ---------------------------------------------------------------------------
// Flash attention (no-max softmax, Q pre-scaled): 512 blocks, XCD swizzle.
// Wave = 32 q-rows, 64 keys/iter. K/V register-prefetched one iteration
// ahead (r8 structure, proven 55.8 us).
// ---------------------------------------------------------------------------
#define PSTRIDE 72
__global__ __launch_bounds__(256) void attn_fused(const unsigned short* __restrict__ Q,
                                                  const unsigned short* __restrict__ Kf,
                                                  const unsigned short* __restrict__ Vf,
                                                  unsigned short* __restrict__ O) {
    const int bidx = blockIdx.x;
    const int g8 = bidx & 7, t = bidx >> 3;
    const int bh = g8 * 4 + (t & 3);
    const int qt = t >> 2;
    const int w = threadIdx.x >> 6, lane = threadIdx.x & 63;
    const int lm = lane & 15, lq = lane >> 4;

    __shared__ __align__(16) unsigned short P[4][32 * PSTRIDE];  // 18.4 KB

    const unsigned short* Qb = Q + (size_t)bh * BH_STRIDE;
    const unsigned short* Kb = Kf + (size_t)bh * BH_STRIDE;
    const unsigned short* Vb = Vf + (size_t)bh * BH_STRIDE;

    const int ga = qt * 8 + w * 2;
    frag_ab qf[2][2];
#pragma unroll
    for (int qi = 0; qi < 2; ++qi) {
        qf[qi][0] = *(const frag_ab*)&Qb[(((ga + qi) * 2 + 0) * 64 + lane) * 8];
        qf[qi][1] = *(const frag_ab*)&Qb[(((ga + qi) * 2 + 1) * 64 + lane) * 8];
    }

    frag_ab vone;
#pragma unroll
    for (int j = 0; j < 8; ++j) vone[j] = (short)0x3F80;   // bf16 1.0

    frag_cd oa[2][4], oc[2];
#pragma unroll
    for (int qi = 0; qi < 2; ++qi) {
        oc[qi] = (frag_cd){0.f, 0.f, 0.f, 0.f};
#pragma unroll
        for (int dt = 0; dt < 4; ++dt) oa[qi][dt] = (frag_cd){0.f, 0.f, 0.f, 0.f};
    }

    // prefetch iteration 0
    frag_ab kc[4][2], vc[2][4];
#pragma unroll
    for (int c = 0; c < 4; ++c) {
        kc[c][0] = *(const frag_ab*)&Kb[((c * 2 + 0) * 64 + lane) * 8];
        kc[c][1] = *(const frag_ab*)&Kb[((c * 2 + 1) * 64 + lane) * 8];
    }
#pragma unroll
    for (int jj = 0; jj < 2; ++jj)
#pragma unroll
        for (int dt = 0; dt < 4; ++dt)
            vc[jj][dt] = *(const frag_ab*)&Vb[((jj * 4 + dt) * 64 + lane) * 8];

    for (int j0 = 0; j0 < SEQ; j0 += 64) {
        // issue next-iteration loads first (modulo wrap: last iter reloads 0)
        const int jn = (j0 + 64) & (SEQ - 1);
        const int kgn = jn >> 4, jbn = jn >> 5;
        frag_ab kn[4][2], vn[2][4];
#pragma unroll
        for (int c = 0; c < 4; ++c) {
            kn[c][0] = *(const frag_ab*)&Kb[(((kgn + c) * 2 + 0) * 64 + lane) * 8];
            kn[c][1] = *(const frag_ab*)&Kb[(((kgn + c) * 2 + 1) * 64 + lane) * 8];
        }
#pragma unroll
        for (int jj = 0; jj < 2; ++jj)
#pragma unroll
            for (int dt = 0; dt < 4; ++dt)
                vn[jj][dt] = *(const frag_ab*)&Vb[(((jbn + jj) * 4 + dt) * 64 + lane) * 8];

        // QK^T + exp2 on current K registers
        const frag_cd z = (frag_cd){0.f, 0.f, 0.f, 0.f};
#pragma unroll
        for (int c = 0; c < 4; ++c) {
#pragma unroll
            for (int qi = 0; qi < 2; ++qi) {
                frag_cd s = __builtin_amdgcn_mfma_f32_16x16x32_bf16(qf[qi][0], kc[c][0], z, 0, 0, 0);
                s = __builtin_amdgcn_mfma_f32_16x16x32_bf16(qf[qi][1], kc[c][1], s, 0, 0, 0);
#pragma unroll
                for (int r = 0; r < 4; ++r) {
                    float p = __builtin_amdgcn_exp2f(s[r]);
                    P[w][(qi * 16 + lq * 4 + r) * PSTRIDE + c * 16 + lm] = f2bf_trunc(p);
                }
            }
        }

        // C-layout -> A-layout via wave-local LDS (in-order DS, no barrier)
        frag_ab pf[2][2];
#pragma unroll
        for (int qi = 0; qi < 2; ++qi) {
            pf[qi][0] = *(const frag_ab*)&P[w][(qi * 16 + lm) * PSTRIDE + lq * 8];
            pf[qi][1] = *(const frag_ab*)&P[w][(qi * 16 + lm) * PSTRIDE + 32 + lq * 8];
            oc[qi] = __builtin_amdgcn_mfma_f32_16x16x32_bf16(pf[qi][0], vone, oc[qi], 0, 0, 0);
            oc[qi] = __builtin_amdgcn_mfma_f32_16x16x32_bf16(pf[qi][1], vone, oc[qi], 0, 0, 0);
        }

#pragma unroll
        for (int dt = 0; dt < 4; ++dt)
#pragma unroll
            for (int qi = 0; qi < 2; ++qi) {
                oa[qi][dt] = __builtin_amdgcn_mfma_f32_16x16x32_bf16(pf[qi][0], vc[0][dt], oa[qi][dt], 0, 0, 0);
                oa[qi][dt] = __builtin_amdgcn_mfma_f32_16x16x32_bf16(pf[qi][1], vc[1][dt], oa[qi][dt], 0, 0, 0);
            }

        // rotate prefetch registers
#pragma unroll
        for (int c = 0; c < 4; ++c) { kc[c][0] = kn[c][0]; kc[c][1] = kn[c][1]; }
#pragma unroll
        for (int jj = 0; jj < 2; ++jj)
#pragma unroll
            for (int dt = 0; dt < 4; ++dt) vc[jj][dt] = vn[jj][dt];
    }

    const int b = bh >> 4, h = bh & (NHEAD - 1);
#pragma unroll
    for (int qi = 0; qi < 2; ++qi) {
        const int q0 = (ga + qi) * 16;
#pragma unroll
        for (int r = 0; r < 4; ++r) {
            float inv = 1.0f / oc[qi][r];
            int srow = q0 + lq * 4 + r;
#pragma unroll
            for (int dt = 0; dt < 4; ++dt) {
                int d = dt * 16 + lm;
                O[((size_t)(b * SEQ + srow)) * EMB + h * HDIM + d] = f2bf(oa[qi][dt][r] * inv);
            }
        }
    }
}

// ---------------------------------------------------------------------------
extern "C" void kernel_launch(void* const* d_in, const int* in_sizes, int n_in,
                              void* d_out, int out_size, void* d_ws, size_t ws_size,
                              hipStream_t stream) {
    const float* x  = (const float*)d_in[0];
    const float* Wq = (const float*)d_in[1];
    const float* bq = (const float*)d_in[2];
    const float* Wk = (const float*)d_in[3];
    const float* bk = (const float*)d_in[4];
    const float* Wv = (const float*)d_in[5];
    const float* bv = (const float*)d_in[6];
    const float* Wo = (const float*)d_in[7];
    const float* bo = (const float*)d_in[8];

    unsigned short* xb    = (unsigned short*)d_ws;
    unsigned short* q_ws  = xb + (size_t)MROWS * EMB;
    unsigned short* k_ws  = q_ws + (size_t)MROWS * EMB;
    unsigned short* vt_ws = k_ws + (size_t)MROWS * EMB;
    unsigned short* o_ws  = xb;     // xb dead after QKV projections
    unsigned short* wqkv  = (unsigned short*)d_out;   // d_out as bf16-W scratch
    unsigned short* wo_b  = q_ws;   // q_ws dead after attn; holds bf16 Wo

    dim3 blk(256);
    cvt_all<<<dim3((MROWS * EMB + 3 * EMB * EMB) / 2048), blk, 0, stream>>>(
        x, Wq, Wk, Wv, xb, wqkv);

    gemm128<true><<<dim3(768), blk, 0, stream>>>(
        xb, wqkv, wqkv + EMB * EMB, wqkv + 2 * EMB * EMB,
        bq, bk, bv, q_ws, k_ws, vt_ws);

    attn_fused<<<dim3(512), blk, 0, stream>>>(q_ws, k_ws, vt_ws, o_ws);

    cvt_bf16<<<dim3(EMB * EMB / 2048), blk, 0, stream>>>(Wo, wo_b, EMB * EMB);
    gemm128<false><<<dim3(256), blk, 0, stream>>>(
        o_ws, wo_b, wo_b, wo_b, bo, bo, bo, d_out, d_out, d_out);
}